// Round 1
// baseline (3089.587 us; speedup 1.0000x reference)
//
#include <hip/hip_runtime.h>

#define B_ 64
#define T_ 512
#define E_ 512
#define HD_ 256
#define G4_ 1024   // 4*HD
#define H_ 512
#define K_ 16
#define NEG_ (-10000.0f)
#define START_ 13
#define STOP_ 14

typedef unsigned int u32;
using bf16x8  = __attribute__((ext_vector_type(8))) __bf16;
using f32x4   = __attribute__((ext_vector_type(4))) float;
using half2v  = __attribute__((ext_vector_type(2))) _Float16;
using ushort4v = __attribute__((ext_vector_type(4))) unsigned short;

__device__ __forceinline__ float bf2f(unsigned short u) {
    u32 x = ((u32)u) << 16;
    return __builtin_bit_cast(float, x);
}
__device__ __forceinline__ unsigned short f2bf(float f) {
    u32 x = __builtin_bit_cast(u32, f);
    x += 0x7fffu + ((x >> 16) & 1u);   // RNE
    return (unsigned short)(x >> 16);
}
__device__ __forceinline__ float dot2h(u32 a, u32 b, float c) {
#if __has_builtin(__builtin_amdgcn_fdot2)
    return __builtin_amdgcn_fdot2(__builtin_bit_cast(half2v, a),
                                  __builtin_bit_cast(half2v, b), c, false);
#else
    half2v ha = __builtin_bit_cast(half2v, a), hb = __builtin_bit_cast(half2v, b);
    return c + (float)ha.x * (float)hb.x + (float)ha.y * (float)hb.y;
#endif
}
__device__ __forceinline__ float sigm(float x) { return 1.f / (1.f + __expf(-x)); }
__device__ __forceinline__ float tanh_f(float x) {
    float a = fabsf(x);
    float e = __expf(-2.f * a);
    float t = (1.f - e) / (1.f + e);
    return x < 0.f ? -t : t;
}

// ---------------- converters ----------------
__global__ void cvt_f16_k(const float* __restrict__ src, _Float16* __restrict__ dst, int n4) {
    int i = blockIdx.x * blockDim.x + threadIdx.x;
    if (i < n4) {
        float4 v = ((const float4*)src)[i];
        half2v a; a.x = (_Float16)v.x; a.y = (_Float16)v.y;
        half2v b; b.x = (_Float16)v.z; b.y = (_Float16)v.w;
        ((u32*)dst)[2 * i]     = __builtin_bit_cast(u32, a);
        ((u32*)dst)[2 * i + 1] = __builtin_bit_cast(u32, b);
    }
}
__global__ void cvt_bf16_k(const float* __restrict__ src, unsigned short* __restrict__ dst, int n4) {
    int i = blockIdx.x * blockDim.x + threadIdx.x;
    if (i < n4) {
        float4 v = ((const float4*)src)[i];
        ushort4v o; o.x = f2bf(v.x); o.y = f2bf(v.y); o.z = f2bf(v.z); o.w = f2bf(v.w);
        ((ushort4v*)dst)[i] = o;
    }
}

// ---------------- embedding gather + cast ----------------
__global__ void embed_k(const int* __restrict__ x, const float* __restrict__ emb,
                        unsigned short* __restrict__ xe) {
    int m = blockIdx.x;                  // 0..32767 = b*T + t
    int row = x[m];
    int c = threadIdx.x * 4;             // 128 threads * 4 = 512
    float4 v = *(const float4*)(emb + (size_t)row * E_ + c);
    ushort4v o; o.x = f2bf(v.x); o.y = f2bf(v.y); o.z = f2bf(v.z); o.w = f2bf(v.w);
    *(ushort4v*)(xe + (size_t)m * E_ + c) = o;
}

// ---------------- bf16 MFMA GEMM:  C[m,n] = sum_k A[m,k]*Bw[n,k]  (C bf16) ----------------
__global__ __launch_bounds__(256) void gemm_bt(const unsigned short* __restrict__ A,
                                               const unsigned short* __restrict__ Bw,
                                               unsigned short* __restrict__ C,
                                               int M, int N, int Kd) {
    __shared__ __align__(16) unsigned short As[128 * 64];
    __shared__ __align__(16) unsigned short Bs[128 * 64];
    const int nTn = N >> 7;
    const int tm = blockIdx.x / nTn, tn = blockIdx.x % nTn;
    const int tid = threadIdx.x;
    const int lane = tid & 63, wave = tid >> 6;
    const int wr = wave >> 1, wc = wave & 1;      // 2x2 waves of 64x64
    f32x4 acc[4][4];
#pragma unroll
    for (int i = 0; i < 4; ++i)
#pragma unroll
        for (int j = 0; j < 4; ++j) acc[i][j] = f32x4{0.f, 0.f, 0.f, 0.f};
    const int lr = lane & 15, lk = (lane >> 4) * 8;

    for (int k0 = 0; k0 < Kd; k0 += 64) {
#pragma unroll
        for (int r = 0; r < 4; ++r) {
            int c = r * 256 + tid;                     // chunk id, 16B each
            const unsigned short* srcA = A + (size_t)(tm * 128 + (c >> 3)) * Kd + k0 + (c & 7) * 8;
            const unsigned short* srcB = Bw + (size_t)(tn * 128 + (c >> 3)) * Kd + k0 + (c & 7) * 8;
            unsigned short* dA = &As[(size_t)(r * 256 + wave * 64) * 8];
            unsigned short* dB = &Bs[(size_t)(r * 256 + wave * 64) * 8];
            __builtin_amdgcn_global_load_lds((const __attribute__((address_space(1))) void*)srcA,
                                             (__attribute__((address_space(3))) void*)dA, 16, 0, 0);
            __builtin_amdgcn_global_load_lds((const __attribute__((address_space(1))) void*)srcB,
                                             (__attribute__((address_space(3))) void*)dB, 16, 0, 0);
        }
        __syncthreads();
#pragma unroll
        for (int kk = 0; kk < 2; ++kk) {
            bf16x8 av[4], bv[4];
#pragma unroll
            for (int i = 0; i < 4; ++i)
                av[i] = *(const bf16x8*)&As[(wr * 64 + i * 16 + lr) * 64 + kk * 32 + lk];
#pragma unroll
            for (int j = 0; j < 4; ++j)
                bv[j] = *(const bf16x8*)&Bs[(wc * 64 + j * 16 + lr) * 64 + kk * 32 + lk];
#pragma unroll
            for (int i = 0; i < 4; ++i)
#pragma unroll
                for (int j = 0; j < 4; ++j)
                    acc[i][j] = __builtin_amdgcn_mfma_f32_16x16x32_bf16(av[i], bv[j], acc[i][j], 0, 0, 0);
        }
        __syncthreads();
    }
    const int mq = (lane >> 4) * 4;
#pragma unroll
    for (int i = 0; i < 4; ++i)
#pragma unroll
        for (int j = 0; j < 4; ++j) {
            int m0 = tm * 128 + wr * 64 + i * 16 + mq;
            int n0 = tn * 128 + wc * 64 + j * 16 + lr;
#pragma unroll
            for (int q = 0; q < 4; ++q)
                C[(size_t)(m0 + q) * N + n0] = f2bf(acc[i][j][q]);
        }
}

// ---------------- LSTM recurrence: one block per (b, dir), 1024 threads = 1024 gate rows ----
#define RU 92   // 92 u32 = 184 f16 of each row in VGPRs
#define TC 9    // 9 uint4 = 72 f16 of each row in LDS
__global__ __launch_bounds__(1024) void lstm_layer_k(
    const _Float16* __restrict__ whh,     // [2][1024][256] (this layer)
    const float* __restrict__ bih,        // [2][1024]
    const float* __restrict__ bhh,        // [2][1024]
    const float* __restrict__ h0,         // [2][64][256]
    const float* __restrict__ c0,         // [2][64][256]
    const unsigned short* __restrict__ Z, // [32768][2048] bf16 gate preacts (x-part)
    unsigned short* __restrict__ Hout) {  // [32768][512] bf16
    __shared__ __align__(16) uint4 wtail[TC * 1024];   // 144 KB, transposed: [chunk][row]
    __shared__ __align__(16) u32 h_shU[128];           // 256 f16
    __shared__ float g_sh[1024];
    const int tid = threadIdx.x;
    const int b = blockIdx.x >> 1, dir = blockIdx.x & 1;

    const u32* wrow = (const u32*)(whh + ((size_t)(dir * 1024 + tid)) * 256);
    u32 w[RU];
#pragma unroll
    for (int i = 0; i < RU; ++i) w[i] = wrow[i];
    {
        const uint4* wrow4 = (const uint4*)wrow;
#pragma unroll
        for (int i = 0; i < TC; ++i) wtail[i * 1024 + tid] = wrow4[23 + i];
    }
    const float bias = bih[dir * 1024 + tid] + bhh[dir * 1024 + tid];
    float c = 0.f;
    if (tid < 256) c = c0[(size_t)dir * B_ * HD_ + b * HD_ + tid];
    if (tid < 128) {
        float x0 = h0[(size_t)dir * B_ * HD_ + b * HD_ + 2 * tid];
        float x1 = h0[(size_t)dir * B_ * HD_ + b * HD_ + 2 * tid + 1];
        half2v hp; hp.x = (_Float16)x0; hp.y = (_Float16)x1;
        h_shU[tid] = __builtin_bit_cast(u32, hp);
    }
    __syncthreads();

    for (int s = 0; s < T_; ++s) {
        const int t = dir ? (T_ - 1 - s) : s;
        const float z = bf2f(Z[(size_t)(b * T_ + t) * 2048 + dir * 1024 + tid]);
        float a0 = 0.f, a1 = 0.f, a2 = 0.f, a3 = 0.f;
        const uint4* h4 = (const uint4*)h_shU;
#pragma unroll
        for (int i = 0; i < 23; ++i) {       // register weights, h broadcast from LDS
            uint4 hv = h4[i];
            a0 = dot2h(w[4 * i + 0], hv.x, a0);
            a1 = dot2h(w[4 * i + 1], hv.y, a1);
            a2 = dot2h(w[4 * i + 2], hv.z, a2);
            a3 = dot2h(w[4 * i + 3], hv.w, a3);
        }
#pragma unroll
        for (int i = 0; i < TC; ++i) {       // LDS-resident tail of the row
            uint4 hv = h4[23 + i];
            uint4 wv = wtail[i * 1024 + tid];
            a0 = dot2h(wv.x, hv.x, a0);
            a1 = dot2h(wv.y, hv.y, a1);
            a2 = dot2h(wv.z, hv.z, a2);
            a3 = dot2h(wv.w, hv.w, a3);
        }
        g_sh[tid] = (a0 + a1) + (a2 + a3) + z + bias;
        __syncthreads();
        if (tid < 256) {
            float ig = sigm(g_sh[tid]);
            float fg = sigm(g_sh[256 + tid]);
            float gg = tanh_f(g_sh[512 + tid]);
            float og = sigm(g_sh[768 + tid]);
            c = fg * c + ig * gg;
            float h = og * tanh_f(c);
            ((_Float16*)h_shU)[tid] = (_Float16)h;
            Hout[(size_t)(b * T_ + t) * H_ + dir * HD_ + tid] = f2bf(h);
        }
        __syncthreads();
    }
}

// ---------------- tag scores: out[m,kk] = H[m,:] . w_out[kk,:] + b_out[kk] ----------------
__global__ __launch_bounds__(256) void tag_k(const unsigned short* __restrict__ Hs,
                                             const float* __restrict__ wout,
                                             const float* __restrict__ bout,
                                             float* __restrict__ out) {
    const int tid = threadIdx.x;
    const int mi = tid >> 4, kk = tid & 15;
    const int m = blockIdx.x * 16 + mi;
    const uint4* hrow = (const uint4*)(Hs + (size_t)m * H_);
    const float4* wrow = (const float4*)(wout + (size_t)kk * H_);
    float acc = 0.f;
#pragma unroll 8
    for (int i = 0; i < 64; ++i) {
        uint4 hv = hrow[i];
        float4 w0 = wrow[2 * i], w1 = wrow[2 * i + 1];
        acc += bf2f((unsigned short)(hv.x & 0xffff)) * w0.x + bf2f((unsigned short)(hv.x >> 16)) * w0.y
             + bf2f((unsigned short)(hv.y & 0xffff)) * w0.z + bf2f((unsigned short)(hv.y >> 16)) * w0.w
             + bf2f((unsigned short)(hv.z & 0xffff)) * w1.x + bf2f((unsigned short)(hv.z >> 16)) * w1.y
             + bf2f((unsigned short)(hv.w & 0xffff)) * w1.z + bf2f((unsigned short)(hv.w >> 16)) * w1.w;
    }
    out[(size_t)m * K_ + kk] = acc + bout[kk];
}

// ---------------- CRF forward (faithful to reference's cross-batch sum) ----------------
__global__ __launch_bounds__(1024) void crf_k(const float* __restrict__ tag,
                                              const float* __restrict__ trans,
                                              float* __restrict__ out) {
    __shared__ float albuf[2][64][17];
    const int tid = threadIdx.x;
    const int kn = tid >> 6, b = tid & 63;   // wave = next-tag, lane = batch
    float trow[16];
#pragma unroll
    for (int kp = 0; kp < 16; ++kp) trow[kp] = trans[kn * 16 + kp];
    albuf[0][b][kn] = (kn == START_) ? 0.f : NEG_;
    __syncthreads();
    int cur = 0;
    for (int t = 0; t < T_; ++t) {
        const float feat = tag[(size_t)(b * T_ + t) * K_ + kn];
        float v[16];
        float m = -3.4e38f;
#pragma unroll
        for (int kp = 0; kp < 16; ++kp) {
            v[kp] = albuf[cur][b][kp] + trow[kp];
            m = fmaxf(m, v[kp]);
        }
        float sm = 0.f;
#pragma unroll
        for (int kp = 0; kp < 16; ++kp) sm += __expf(v[kp] - m);
#pragma unroll
        for (int off = 32; off >= 1; off >>= 1) sm += __shfl_xor(sm, off, 64);
        albuf[cur ^ 1][b][kn] = feat + m + __logf(sm);
        __syncthreads();
        cur ^= 1;
    }
    const float term = albuf[cur][b][kn] + trans[STOP_ * 16 + kn];
    albuf[cur ^ 1][b][kn] = term;
    __syncthreads();
    if (tid < 64) {   // all in wave 0
        float mb = -3.4e38f;
#pragma unroll
        for (int k2 = 0; k2 < 16; ++k2) mb = fmaxf(mb, albuf[cur ^ 1][tid][k2]);
        float p = 0.f;
#pragma unroll
        for (int k2 = 0; k2 < 16; ++k2) p += __expf(albuf[cur ^ 1][tid][k2] - mb);
#pragma unroll
        for (int off = 32; off >= 1; off >>= 1) p += __shfl_xor(p, off, 64);
        out[(size_t)B_ * T_ * K_ + tid] = mb + __logf(p);
    }
}

extern "C" void kernel_launch(void* const* d_in, const int* in_sizes, int n_in,
                              void* d_out, int out_size, void* d_ws, size_t ws_size,
                              hipStream_t stream) {
    const int*   x     = (const int*)d_in[0];
    const float* emb   = (const float*)d_in[2];
    const float* w_ih  = (const float*)d_in[3];
    const float* w_hh  = (const float*)d_in[4];
    const float* b_ih  = (const float*)d_in[5];
    const float* b_hh  = (const float*)d_in[6];
    const float* h0    = (const float*)d_in[7];
    const float* c0    = (const float*)d_in[8];
    const float* w_out = (const float*)d_in[9];
    const float* b_out = (const float*)d_in[10];
    const float* trans = (const float*)d_in[11];
    float* out = (float*)d_out;

    // workspace layout (≈198 MB)
    char* ws = (char*)d_ws;
    _Float16*       whh16 = (_Float16*)ws;                               // 2 MB  [L][2][1024][256] f16
    unsigned short* wih16 = (unsigned short*)(ws + ((size_t)2 << 20));   // 4 MB  [L][2048][512] bf16
    unsigned short* xe    = (unsigned short*)(ws + ((size_t)6 << 20));   // 32 MB [32768][512] bf16 (reused as H1)
    unsigned short* Zb    = (unsigned short*)(ws + ((size_t)38 << 20));  // 128 MB [32768][2048] bf16
    unsigned short* H0b   = (unsigned short*)(ws + ((size_t)166 << 20)); // 32 MB [32768][512] bf16
    if (ws_size < ((size_t)199 << 20)) return;  // workspace too small: leave output untouched (visible as abs failure)

    cvt_f16_k<<<1024, 256, 0, stream>>>(w_hh, whh16, 1048576 / 4);
    cvt_bf16_k<<<2048, 256, 0, stream>>>(w_ih, wih16, 2097152 / 4);
    embed_k<<<B_ * T_, 128, 0, stream>>>(x, emb, xe);

    // layer 0
    gemm_bt<<<(32768 / 128) * (2048 / 128), 256, 0, stream>>>(xe, wih16, Zb, 32768, 2048, 512);
    lstm_layer_k<<<128, 1024, 0, stream>>>(whh16, b_ih, b_hh, h0, c0, Zb, H0b);
    // layer 1
    gemm_bt<<<(32768 / 128) * (2048 / 128), 256, 0, stream>>>(H0b, wih16 + (size_t)2048 * 512, Zb, 32768, 2048, 512);
    lstm_layer_k<<<128, 1024, 0, stream>>>(whh16 + (size_t)2 * 1024 * 256, b_ih + 2048, b_hh + 2048,
                                           h0 + 2 * B_ * HD_, c0 + 2 * B_ * HD_, Zb, xe /*H1*/);
    // emissions + CRF
    tag_k<<<32768 / 16, 256, 0, stream>>>(xe, w_out, b_out, out);
    crf_k<<<1, 1024, 0, stream>>>(out, trans, out);
}